// Round 8
// baseline (461.584 us; speedup 1.0000x reference)
//
#include <hip/hip_runtime.h>

#define B_   2
#define S_   2048
#define D_   1024
#define H_   16
#define DK_  64
#define DFF_ 4096
#define NTOK (B_ * S_)   // 4096

#define QSCALE 0.18033688011112042f   // 0.125 * log2(e)

typedef __bf16 bf16x8 __attribute__((ext_vector_type(8)));
typedef __bf16 bf16x4 __attribute__((ext_vector_type(4)));
typedef float  f32x4  __attribute__((ext_vector_type(4)));

#if __has_builtin(__builtin_amdgcn_exp2f)
#define EXP2(x) __builtin_amdgcn_exp2f(x)
#else
#define EXP2(x) exp2f(x)
#endif

// async global->LDS 16B copy. LDS dest is wave-uniform base + lane*16.
__device__ __forceinline__ void ld16(const __bf16* g, __bf16* l) {
  __builtin_amdgcn_global_load_lds(
      (const __attribute__((address_space(1))) void*)g,
      (__attribute__((address_space(3))) void*)l, 16, 0, 0);
}

// ---------------------------------------------------------------------------
// XCD-aware block swizzle (R5). XCD = flat % 8; compact C-patch per XCD.
// ---------------------------------------------------------------------------
__device__ __forceinline__ void xcd_swizzle(int& bx, int& by) {
  const int gx = gridDim.x;
  const int flat = blockIdx.y * gx + blockIdx.x;
  const int x = flat & 7;
  const int n = flat >> 3;
  if (gx == 32) {
    const int px = (x & 1) << 4, py = (x >> 1) << 3;
    const int g = n >> 5, rem = n & 31;
    bx = px + (g << 2) + (rem & 3);
    by = py + (rem >> 2);
  } else {
    const int g = n >> 4, rem = n & 15;
    bx = (g << 2) + (rem & 3);
    by = (x << 2) + (rem >> 2);
  }
}

// ---------------------------------------------------------------------------
// GEMM core, BK=64 (R5): 32 MFMA per barrier. Interleaved-k LDS layout,
// conflict-free b128 frag reads, staging 64B-coalesced. 32 KB LDS.
// ---------------------------------------------------------------------------
__device__ __forceinline__ void gemm_core_128(
    const __bf16* __restrict__ A, const __bf16* __restrict__ W,
    int ld, int kLen, int rowA0, int rowW0,
    f32x4 (&acc)[4][4], __bf16* As, __bf16* Bs)
{
  const int t    = threadIdx.x;
  const int lane = t & 63;
  const int wv   = t >> 6;
  const int wm   = (wv >> 1) << 6;
  const int wn   = (wv & 1) << 6;
  const int l15  = lane & 15;
  const int q4   = lane >> 4;

#pragma unroll
  for (int i = 0; i < 4; ++i)
#pragma unroll
    for (int j = 0; j < 4; ++j)
      acc[i][j] = (f32x4){0.f, 0.f, 0.f, 0.f};

  const __bf16* gA = A + (size_t)(rowA0 + 32 * wv + l15) * ld + q4 * 8;
  const __bf16* gW = W + (size_t)(rowW0 + 32 * wv + l15) * ld + q4 * 8;
  __bf16* lA = As + wv * 2048;
  __bf16* lB = Bs + wv * 2048;
  const size_t r16 = (size_t)16 * ld;

  const int fbg = (q4 << 7) + (l15 << 3);
  const int ia = (wm >> 4);
  const int ib = (wn >> 4);

  for (int k0 = 0; k0 < kLen; k0 += 64) {
    ld16(gA + k0,            lA);
    ld16(gA + k0 + 32,       lA + 512);
    ld16(gA + k0 + r16,      lA + 1024);
    ld16(gA + k0 + r16 + 32, lA + 1536);
    ld16(gW + k0,            lB);
    ld16(gW + k0 + 32,       lB + 512);
    ld16(gW + k0 + r16,      lB + 1024);
    ld16(gW + k0 + r16 + 32, lB + 1536);
    __syncthreads();
#pragma unroll
    for (int s = 0; s < 2; ++s) {
      bf16x8 af[4], bw[4];
#pragma unroll
      for (int i = 0; i < 4; ++i)
        af[i] = *(const bf16x8*)(As + (ia + i) * 1024 + s * 512 + fbg);
#pragma unroll
      for (int j = 0; j < 4; ++j)
        bw[j] = *(const bf16x8*)(Bs + (ib + j) * 1024 + s * 512 + fbg);
#pragma unroll
      for (int i = 0; i < 4; ++i)
#pragma unroll
        for (int j = 0; j < 4; ++j)
          acc[i][j] = __builtin_amdgcn_mfma_f32_16x16x32_bf16(af[i], bw[j], acc[i][j], 0, 0, 0);
    }
    __syncthreads();
  }
}

// ---------------------------------------------------------------------------
// QKV: grid.z selects {Q,K,V}. Q pre-scaled; V stored transposed vt[b,h,d,s].
// ---------------------------------------------------------------------------
__global__ __launch_bounds__(256) void gemm_qkv(
    const __bf16* __restrict__ xn,
    const __bf16* __restrict__ wqb, const __bf16* __restrict__ wkb,
    const __bf16* __restrict__ wvb,
    __bf16* __restrict__ qo, __bf16* __restrict__ ko, __bf16* __restrict__ vto)
{
  __shared__ __align__(16) __bf16 As[128 * 64];
  __shared__ __align__(16) __bf16 Bs[128 * 64];
  int bx, by; xcd_swizzle(bx, by);
  const __bf16* W = blockIdx.z == 0 ? wqb : (blockIdx.z == 1 ? wkb : wvb);
  f32x4 acc[4][4];
  gemm_core_128(xn, W, D_, D_, by * 128, bx * 128, acc, As, Bs);

  const int t = threadIdx.x, lane = t & 63, wv = t >> 6;
  const int wm = (wv >> 1) << 6, wn = (wv & 1) << 6;
  const int l15 = lane & 15, q4 = lane >> 4;
  const int row0 = by * 128 + wm;
  const int col0 = bx * 128 + wn;

  if (blockIdx.z < 2) {
    __bf16* o = blockIdx.z == 0 ? qo : ko;
    const float sc = blockIdx.z == 0 ? QSCALE : 1.0f;
#pragma unroll
    for (int i = 0; i < 4; ++i)
#pragma unroll
      for (int j = 0; j < 4; ++j)
#pragma unroll
        for (int r = 0; r < 4; ++r) {
          int row = row0 + 16 * i + q4 * 4 + r;
          int col = col0 + 16 * j + l15;
          o[(size_t)row * D_ + col] = (__bf16)(acc[i][j][r] * sc);
        }
  } else {
#pragma unroll
    for (int i = 0; i < 4; ++i)
#pragma unroll
      for (int j = 0; j < 4; ++j) {
        int tok0 = row0 + 16 * i + q4 * 4;
        int c    = col0 + 16 * j + l15;
        int b0 = tok0 >> 11, s0 = tok0 & (S_ - 1);
        int hh = c >> 6, dd = c & (DK_ - 1);
        bf16x4 pk;
#pragma unroll
        for (int r = 0; r < 4; ++r) pk[r] = (__bf16)acc[i][j][r];
        *(bf16x4*)&vto[(size_t)((b0 * H_ + hh) * DK_ + dd) * S_ + s0] = pk;
      }
  }
}

// ---------------------------------------------------------------------------
// FFN1 GEMM: h = relu(A @ W^T + bias) -> bf16.
// ---------------------------------------------------------------------------
__global__ __launch_bounds__(256) void gemm_ffn1(
    const __bf16* __restrict__ A, const __bf16* __restrict__ W,
    __bf16* __restrict__ outb, const float* __restrict__ bias)
{
  __shared__ __align__(16) __bf16 As[128 * 64];
  __shared__ __align__(16) __bf16 Bs[128 * 64];
  int bx, by; xcd_swizzle(bx, by);
  f32x4 acc[4][4];
  gemm_core_128(A, W, D_, D_, by * 128, bx * 128, acc, As, Bs);

  const int t = threadIdx.x, lane = t & 63, wv = t >> 6;
  const int wm = (wv >> 1) << 6, wn = (wv & 1) << 6;
  const int l15 = lane & 15, q4 = lane >> 4;
  const int row0 = by * 128 + wm;
  const int col0 = bx * 128 + wn;

#pragma unroll
  for (int i = 0; i < 4; ++i)
#pragma unroll
    for (int j = 0; j < 4; ++j) {
      int col = col0 + 16 * j + l15;
      float bs = bias[col];
#pragma unroll
      for (int r = 0; r < 4; ++r) {
        int row = row0 + 16 * i + q4 * 4 + r;
        float v = fmaxf(acc[i][j][r] + bs, 0.0f);
        outb[(size_t)row * DFF_ + col] = (__bf16)v;
      }
    }
}

// ---------------------------------------------------------------------------
// split-K GEMM with f32 atomic-add epilogue (N = 1024). dst must be
// pre-initialized (x1 = x for O-proj; d_out = x1 + b2 for FFN2). Replaces
// partial buffers + reduce kernels (R7: ~110 MB partial traffic + 1 launch).
// ---------------------------------------------------------------------------
__global__ __launch_bounds__(256) void gemm_splitk_atomic(
    const __bf16* __restrict__ A, const __bf16* __restrict__ W,
    int K, int kPart, float* __restrict__ dst)
{
  __shared__ __align__(16) __bf16 As[128 * 64];
  __shared__ __align__(16) __bf16 Bs[128 * 64];
  int bx, by; xcd_swizzle(bx, by);
  f32x4 acc[4][4];
  const int z = blockIdx.z;
  gemm_core_128(A + (size_t)z * kPart, W + (size_t)z * kPart, K, kPart,
                by * 128, bx * 128, acc, As, Bs);

  const int t = threadIdx.x, lane = t & 63, wv = t >> 6;
  const int wm = (wv >> 1) << 6, wn = (wv & 1) << 6;
  const int l15 = lane & 15, q4 = lane >> 4;
  const int row0 = by * 128 + wm;
  const int col0 = bx * 128 + wn;

#pragma unroll
  for (int i = 0; i < 4; ++i)
#pragma unroll
    for (int j = 0; j < 4; ++j)
#pragma unroll
      for (int r = 0; r < 4; ++r) {
        int row = row0 + 16 * i + q4 * 4 + r;
        int col = col0 + 16 * j + l15;
        atomicAdd(&dst[(size_t)row * D_ + col], acc[i][j][r]);
      }
}

// ---------------------------------------------------------------------------
// LN2 + d_out base: xn2 = LN(x1); d_out = x1 + b2 (x1 already final via
// atomics). 1 block/row.
// ---------------------------------------------------------------------------
__global__ __launch_bounds__(256) void ln_dout_kernel(
    const float* __restrict__ x1, const float* __restrict__ alpha,
    const float* __restrict__ bias, const float* __restrict__ b2,
    __bf16* __restrict__ xn2, float* __restrict__ dout)
{
  const int row = blockIdx.x;
  const int t = threadIdx.x;
  const size_t base = (size_t)row * D_;
  const float4 v = ((const float4*)(x1 + base))[t];
  const float4 bb = ((const float4*)b2)[t];
  float4 o4;
  o4.x = v.x + bb.x; o4.y = v.y + bb.y; o4.z = v.z + bb.z; o4.w = v.w + bb.w;
  ((float4*)(dout + base))[t] = o4;

  float s  = v.x + v.y + v.z + v.w;
  float ss = v.x * v.x + v.y * v.y + v.z * v.z + v.w * v.w;
#pragma unroll
  for (int m = 1; m < 64; m <<= 1) {
    s  += __shfl_xor(s, m);
    ss += __shfl_xor(ss, m);
  }
  __shared__ float red[8];
  if ((t & 63) == 0) { red[t >> 6] = s; red[4 + (t >> 6)] = ss; }
  __syncthreads();
  s  = red[0] + red[1] + red[2] + red[3];
  ss = red[4] + red[5] + red[6] + red[7];
  const float mean = s * (1.0f / D_);
  float var = (ss - (float)D_ * mean * mean) * (1.0f / (D_ - 1));
  var = fmaxf(var, 0.0f);
  const float inv = 1.0f / (sqrtf(var) + 1e-6f);
  const float4 al = ((const float4*)alpha)[t];
  const float4 bi = ((const float4*)bias)[t];
  bf16x4 o;
  o.x = (__bf16)(al.x * (v.x - mean) * inv + bi.x);
  o.y = (__bf16)(al.y * (v.y - mean) * inv + bi.y);
  o.z = (__bf16)(al.z * (v.z - mean) * inv + bi.z);
  o.w = (__bf16)(al.w * (v.w - mean) * inv + bi.w);
  ((bf16x4*)(xn2 + base))[t] = o;
}

// ---------------------------------------------------------------------------
// weight f32->bf16 casts (jobs 0-5) + LN1 (job 6) + x->x1 copy (job 7).
// grid (4096, 8).
// ---------------------------------------------------------------------------
struct CastJobs {
  const float* src[6];
  __bf16* dst[6];
  int n4[6];
};

__global__ __launch_bounds__(256) void cast_ln_kernel(
    CastJobs cj, const float* __restrict__ x, const float* __restrict__ alpha,
    const float* __restrict__ bias, __bf16* __restrict__ xn1,
    float* __restrict__ x1)
{
  const int j = blockIdx.y;
  if (j < 6) {
    const int i = blockIdx.x * 256 + threadIdx.x;
    if (i < cj.n4[j]) {
      float4 v = ((const float4*)cj.src[j])[i];
      bf16x4 o;
      o.x = (__bf16)v.x; o.y = (__bf16)v.y; o.z = (__bf16)v.z; o.w = (__bf16)v.w;
      ((bf16x4*)cj.dst[j])[i] = o;
    }
    return;
  }
  if (j == 7) {   // x -> x1 (f32 copy), base for O-proj atomic accumulation
    const int i = blockIdx.x * 256 + threadIdx.x;
    ((float4*)x1)[i] = ((const float4*)x)[i];
    return;
  }
  // j == 6: LN1, one block per row (grid.x == NTOK)
  const int row = blockIdx.x;
  const int t = threadIdx.x;
  const float4 v = ((const float4*)(x + (size_t)row * D_))[t];
  float s  = v.x + v.y + v.z + v.w;
  float ss = v.x * v.x + v.y * v.y + v.z * v.z + v.w * v.w;
#pragma unroll
  for (int m = 1; m < 64; m <<= 1) {
    s  += __shfl_xor(s, m);
    ss += __shfl_xor(ss, m);
  }
  __shared__ float red[8];
  if ((t & 63) == 0) { red[t >> 6] = s; red[4 + (t >> 6)] = ss; }
  __syncthreads();
  s  = red[0] + red[1] + red[2] + red[3];
  ss = red[4] + red[5] + red[6] + red[7];
  const float mean = s * (1.0f / D_);
  float var = (ss - (float)D_ * mean * mean) * (1.0f / (D_ - 1));
  var = fmaxf(var, 0.0f);
  const float inv = 1.0f / (sqrtf(var) + 1e-6f);
  const float4 al = ((const float4*)alpha)[t];
  const float4 bi = ((const float4*)bias)[t];
  bf16x4 o;
  o.x = (__bf16)(al.x * (v.x - mean) * inv + bi.x);
  o.y = (__bf16)(al.y * (v.y - mean) * inv + bi.y);
  o.z = (__bf16)(al.z * (v.z - mean) * inv + bi.z);
  o.w = (__bf16)(al.w * (v.w - mean) * inv + bi.w);
  ((bf16x4*)(xn1 + (size_t)row * D_))[t] = o;
}

// ---------------------------------------------------------------------------
// flash attention, BQ=128 (R7-verified): wave owns 32 q-cols, Q B-frags in
// registers, K/V LDS reads amortized over 2x MFMA. Fixed-max softmax.
// LDS = 8K(Ks)+8K(Vt)+18K(Ps) = 34 KB. Grid 512 = 2 blocks/CU.
// ---------------------------------------------------------------------------
__global__ __launch_bounds__(256) void attn_kernel(
    const __bf16* __restrict__ qg, const __bf16* __restrict__ kg,
    const __bf16* __restrict__ vtg, const int* __restrict__ mask,
    __bf16* __restrict__ av)
{
  __shared__ __align__(16) __bf16 Ks[64 * 64];
  __shared__ __align__(16) __bf16 Vt[64 * 64];
  __shared__ __align__(16) __bf16 Ps[128 * 72];

  const int t = threadIdx.x, lane = t & 63, wv = t >> 6;
  const int l15 = lane & 15, q4 = lane >> 4;
  const int bh = blockIdx.x;
  const int b = bh >> 4, h = bh & (H_ - 1);
  const int q0 = blockIdx.y * 128;

  const int srow = lane & 7, sc8 = lane >> 3;
  const __bf16* qg0 = qg + (size_t)(b * S_ + q0 + 32 * wv + srow) * D_ + h * DK_ + sc8 * 8;
  __bf16* lQ = Ps + wv * 2304;
#pragma unroll
  for (int p = 0; p < 4; ++p)
    ld16(qg0 + (size_t)(8 * p) * D_, lQ + 512 * p);

  const __bf16* kg0 = kg + (size_t)(b * S_ + 16 * wv + srow) * D_ + h * DK_ + sc8 * 8;
  const __bf16* vt0 = vtg + (size_t)(bh * DK_ + 16 * wv + srow) * S_ + sc8 * 8;

  const int fb = ((l15 >> 3) << 9) + (q4 << 6) + ((l15 & 7) << 3);
  const int mrow = b * S_;

  float lsum[2] = {0.0f, 0.0f};
  f32x4 oacc[2][4];
#pragma unroll
  for (int m = 0; m < 2; ++m)
#pragma unroll
    for (int jd = 0; jd < 4; ++jd) oacc[m][jd] = (f32x4){0.f, 0.f, 0.f, 0.f};
  bf16x8 bq[2][2];

  for (int kv0 = 0; kv0 < S_; kv0 += 64) {
    ld16(kg0 + (size_t)kv0 * D_,       Ks + wv * 1024);
    ld16(kg0 + (size_t)(kv0 + 8) * D_, Ks + wv * 1024 + 512);
    ld16(vt0 + kv0,                    Vt + wv * 1024);
    ld16(vt0 + (size_t)8 * S_ + kv0,   Vt + wv * 1024 + 512);
    const int mv = mask[mrow + kv0 + lane];
    const bool dirty = (__ballot(mv == 0) != 0ull);
    __syncthreads();

    if (kv0 == 0) {
#pragma unroll
      for (int j = 0; j < 2; ++j)
#pragma unroll
        for (int s = 0; s < 2; ++s)
          bq[j][s] = *(const bf16x8*)(lQ + j * 1024 + s * 256 + fb);
    }

    f32x4 sacc[4][2];
#pragma unroll
    for (int i = 0; i < 4; ++i)
#pragma unroll
      for (int j = 0; j < 2; ++j) sacc[i][j] = (f32x4){0.f, 0.f, 0.f, 0.f};
#pragma unroll
    for (int i = 0; i < 4; ++i)
#pragma unroll
      for (int s = 0; s < 2; ++s) {
        bf16x8 ak = *(const bf16x8*)(Ks + i * 1024 + fb + s * 256);
#pragma unroll
        for (int j = 0; j < 2; ++j)
          sacc[i][j] = __builtin_amdgcn_mfma_f32_16x16x32_bf16(ak, bq[j][s], sacc[i][j], 0, 0, 0);
      }

    if (dirty) {
#pragma unroll
      for (int i = 0; i < 4; ++i)
#pragma unroll
        for (int r = 0; r < 4; ++r)
          if (mask[mrow + kv0 + 16 * i + 4 * q4 + r] == 0) {
            sacc[i][0][r] = -1e30f;
            sacc[i][1][r] = -1e30f;
          }
    }

#pragma unroll
    for (int j = 0; j < 2; ++j) {
      float rs = 0.0f;
#pragma unroll
      for (int i = 0; i < 4; ++i) {
        bf16x4 pb;
#pragma unroll
        for (int r = 0; r < 4; ++r) {
          float pp = EXP2(sacc[i][j][r]);
          rs += pp;
          pb[r] = (__bf16)pp;
        }
        *(bf16x4*)(Ps + (wv * 32 + j * 16 + l15) * 72 + 16 * i + q4 * 4) = pb;
      }
      lsum[j] += rs;
    }

    bf16x8 ap[2][2];
#pragma unroll
    for (int m = 0; m < 2; ++m)
#pragma unroll
      for (int s = 0; s < 2; ++s)
        ap[m][s] = *(const bf16x8*)(Ps + (wv * 32 + 16 * m + l15) * 72 + s * 32 + q4 * 8);
#pragma unroll
    for (int jd = 0; jd < 4; ++jd)
#pragma unroll
      for (int s = 0; s < 2; ++s) {
        bf16x8 bv = *(const bf16x8*)(Vt + jd * 1024 + fb + s * 256);
#pragma unroll
        for (int m = 0; m < 2; ++m)
          oacc[m][jd] = __builtin_amdgcn_mfma_f32_16x16x32_bf16(ap[m][s], bv, oacc[m][jd], 0, 0, 0);
      }
    __syncthreads();
  }

#pragma unroll
  for (int j = 0; j < 2; ++j) {
    lsum[j] += __shfl_xor(lsum[j], 16);
    lsum[j] += __shfl_xor(lsum[j], 32);
  }
  float lt[2][4];
#pragma unroll
  for (int m = 0; m < 2; ++m)
#pragma unroll
    for (int r = 0; r < 4; ++r) lt[m][r] = 1.0f / __shfl(lsum[m], q4 * 4 + r);
#pragma unroll
  for (int m = 0; m < 2; ++m)
#pragma unroll
    for (int jd = 0; jd < 4; ++jd)
#pragma unroll
      for (int r = 0; r < 4; ++r) {
        int tok = b * S_ + q0 + wv * 32 + 16 * m + q4 * 4 + r;
        int c   = h * DK_ + jd * 16 + l15;
        av[(size_t)tok * D_ + c] = (__bf16)(oacc[m][jd][r] * lt[m][r]);
      }
}

// ---------------------------------------------------------------------------
extern "C" void kernel_launch(void* const* d_in, const int* in_sizes, int n_in,
                              void* d_out, int out_size, void* d_ws, size_t ws_size,
                              hipStream_t stream) {
  const float* x      = (const float*)d_in[0];
  const int*   mask   = (const int*)d_in[1];
  const float* wq     = (const float*)d_in[2];
  const float* wk     = (const float*)d_in[3];
  const float* wv     = (const float*)d_in[4];
  const float* wo     = (const float*)d_in[5];
  const float* w1     = (const float*)d_in[6];
  const float* b1     = (const float*)d_in[7];
  const float* w2     = (const float*)d_in[8];
  const float* b2     = (const float*)d_in[9];
  const float* alpha1 = (const float*)d_in[10];
  const float* bias1  = (const float*)d_in[11];
  const float* alpha2 = (const float*)d_in[12];
  const float* bias2  = (const float*)d_in[13];

  // ws layout (MB offsets), peak 80 MB:
  //  0-2 wqb | 2-4 wkb | 4-6 wvb | 6-8 wob | 8-16 w1b | 16-24 w2b
  // 24-32 xn1 (dead after QKV) | 32-40 qb | 40-48 kb | 48-56 vtb (dead after attn)
  // 56-64 avb (dead after O-proj) -> xn2 | 24-56 hb (over dead xn1/qb/kb/vtb)
  // 64-80 x1 (init = x, O-proj atomic target, live till end)
  char* ws = (char*)d_ws;
  __bf16* wqb = (__bf16*)(ws + ((size_t)0 << 20));
  __bf16* wkb = (__bf16*)(ws + ((size_t)2 << 20));
  __bf16* wvb = (__bf16*)(ws + ((size_t)4 << 20));
  __bf16* wob = (__bf16*)(ws + ((size_t)6 << 20));
  __bf16* w1b = (__bf16*)(ws + ((size_t)8 << 20));
  __bf16* w2b = (__bf16*)(ws + ((size_t)16 << 20));
  __bf16* xn1 = (__bf16*)(ws + ((size_t)24 << 20));
  __bf16* qb  = (__bf16*)(ws + ((size_t)32 << 20));
  __bf16* kb  = (__bf16*)(ws + ((size_t)40 << 20));
  __bf16* vtb = (__bf16*)(ws + ((size_t)48 << 20));
  __bf16* avb = (__bf16*)(ws + ((size_t)56 << 20));
  float*  x1  = (float*) (ws + ((size_t)64 << 20));
  __bf16* xn2 = (__bf16*)(ws + ((size_t)56 << 20));
  __bf16* hb  = (__bf16*)(ws + ((size_t)24 << 20));

  CastJobs cj;
  cj.src[0] = wq; cj.dst[0] = wqb; cj.n4[0] = D_ * D_ / 4;
  cj.src[1] = wk; cj.dst[1] = wkb; cj.n4[1] = D_ * D_ / 4;
  cj.src[2] = wv; cj.dst[2] = wvb; cj.n4[2] = D_ * D_ / 4;
  cj.src[3] = wo; cj.dst[3] = wob; cj.n4[3] = D_ * D_ / 4;
  cj.src[4] = w1; cj.dst[4] = w1b; cj.n4[4] = DFF_ * D_ / 4;
  cj.src[5] = w2; cj.dst[5] = w2b; cj.n4[5] = DFF_ * D_ / 4;

  // casts + LN1 + x->x1 copy (grid.x = 4096 covers all jobs exactly)
  cast_ln_kernel<<<dim3(NTOK, 8), 256, 0, stream>>>(
      cj, x, alpha1, bias1, xn1, x1);

  gemm_qkv<<<dim3(D_ / 128, NTOK / 128, 3), 256, 0, stream>>>(
      xn1, wqb, wkb, wvb, qb, kb, vtb);

  attn_kernel<<<dim3(B_ * H_, S_ / 128), 256, 0, stream>>>(qb, kb, vtb, mask, avb);

  // O-proj split-K x2, atomic into x1 (= x + av @ wo^T)
  gemm_splitk_atomic<<<dim3(D_ / 128, NTOK / 128, 2), 256, 0, stream>>>(
      avb, wob, D_, D_ / 2, x1);

  // LN2 + d_out base: xn2 = LN(x1); d_out = x1 + b2
  ln_dout_kernel<<<dim3(NTOK), 256, 0, stream>>>(
      x1, alpha2, bias2, b2, xn2, (float*)d_out);

  // FFN1: h = relu(xn2 @ w1^T + b1)
  gemm_ffn1<<<dim3(DFF_ / 128, NTOK / 128), 256, 0, stream>>>(
      xn2, w1b, hb, b1);

  // FFN2 split-K x4, atomic into d_out (= x1 + b2 + h @ w2^T)
  gemm_splitk_atomic<<<dim3(D_ / 128, NTOK / 128, 4), 256, 0, stream>>>(
      hb, w2b, DFF_, DFF_ / 4, (float*)d_out);
}

// Round 9
// 421.407 us; speedup vs baseline: 1.0953x; 1.0953x over previous
//
#include <hip/hip_runtime.h>

#define B_   2
#define S_   2048
#define D_   1024
#define H_   16
#define DK_  64
#define DFF_ 4096
#define NTOK (B_ * S_)   // 4096

#define QSCALE 0.18033688011112042f   // 0.125 * log2(e)

typedef __bf16 bf16x8 __attribute__((ext_vector_type(8)));
typedef __bf16 bf16x4 __attribute__((ext_vector_type(4)));
typedef float  f32x4  __attribute__((ext_vector_type(4)));

#if __has_builtin(__builtin_amdgcn_exp2f)
#define EXP2(x) __builtin_amdgcn_exp2f(x)
#else
#define EXP2(x) exp2f(x)
#endif

// async global->LDS 16B copy. LDS dest is wave-uniform base + lane*16.
__device__ __forceinline__ void ld16(const __bf16* g, __bf16* l) {
  __builtin_amdgcn_global_load_lds(
      (const __attribute__((address_space(1))) void*)g,
      (__attribute__((address_space(3))) void*)l, 16, 0, 0);
}

// ---------------------------------------------------------------------------
// XCD-aware block swizzle (R5). XCD = flat % 8; compact C-patch per XCD.
// ---------------------------------------------------------------------------
__device__ __forceinline__ void xcd_swizzle(int& bx, int& by) {
  const int gx = gridDim.x;
  const int flat = blockIdx.y * gx + blockIdx.x;
  const int x = flat & 7;
  const int n = flat >> 3;
  if (gx == 32) {
    const int px = (x & 1) << 4, py = (x >> 1) << 3;
    const int g = n >> 5, rem = n & 31;
    bx = px + (g << 2) + (rem & 3);
    by = py + (rem >> 2);
  } else {
    const int g = n >> 4, rem = n & 15;
    bx = (g << 2) + (rem & 3);
    by = (x << 2) + (rem >> 2);
  }
}

// ---------------------------------------------------------------------------
// GEMM core, BK=32 PING-PONG (R9): ONE barrier per K-iter; the barrier's
// vmcnt(0) drains loads issued a full iteration earlier (true prefetch).
// Safety: barrier at iter n proves all waves finished iter n-1's compute on
// buf[(n-1)&1] — exactly the buffer iter n stages into. LDS 2x8KB per
// operand = 32 KB total (same occupancy as R7's BK=64). Interleaved-k
// layout (R2-verified conflict-free): buf stride 4096 elem, group stride 512.
// ---------------------------------------------------------------------------
__device__ __forceinline__ void gemm_core_128(
    const __bf16* __restrict__ A, const __bf16* __restrict__ W,
    int ld, int kLen, int rowA0, int rowW0,
    f32x4 (&acc)[4][4], __bf16* As, __bf16* Bs)
{
  const int t    = threadIdx.x;
  const int lane = t & 63;
  const int wv   = t >> 6;
  const int wm   = (wv >> 1) << 6;
  const int wn   = (wv & 1) << 6;
  const int l15  = lane & 15;
  const int q4   = lane >> 4;

#pragma unroll
  for (int i = 0; i < 4; ++i)
#pragma unroll
    for (int j = 0; j < 4; ++j)
      acc[i][j] = (f32x4){0.f, 0.f, 0.f, 0.f};

  // staging map (R2): wave wv stages row-groups 2wv,2wv+1; lane -> row l15,
  // k-chunk q4. One ld16 = 16 rows x 32 k.
  const __bf16* gA = A + (size_t)(rowA0 + 32 * wv + l15) * ld + q4 * 8;
  const __bf16* gW = W + (size_t)(rowW0 + 32 * wv + l15) * ld + q4 * 8;
  const size_t r16 = (size_t)16 * ld;

  // prologue: stage k-slab 0 into buffer 0
  ld16(gA,       As + wv * 1024);
  ld16(gA + r16, As + wv * 1024 + 512);
  ld16(gW,       Bs + wv * 1024);
  ld16(gW + r16, Bs + wv * 1024 + 512);

  const int fbg = (q4 << 7) + (l15 << 3);
  const int ia = (wm >> 4);
  const int ib = (wn >> 4);

  for (int k0 = 0; k0 < kLen; k0 += 32) {
    const int cur = (k0 >> 5) & 1;
    __syncthreads();   // buf[cur] loads (issued last iter) drained; buf[cur^1] free
    if (k0 + 32 < kLen) {
      const int nb = (cur ^ 1) * 4096;
      ld16(gA + k0 + 32,       As + nb + wv * 1024);
      ld16(gA + k0 + 32 + r16, As + nb + wv * 1024 + 512);
      ld16(gW + k0 + 32,       Bs + nb + wv * 1024);
      ld16(gW + k0 + 32 + r16, Bs + nb + wv * 1024 + 512);
    }
    const int cb = cur * 4096;
    bf16x8 af[4], bw[4];
#pragma unroll
    for (int i = 0; i < 4; ++i)
      af[i] = *(const bf16x8*)(As + cb + (ia + i) * 512 + fbg);
#pragma unroll
    for (int j = 0; j < 4; ++j)
      bw[j] = *(const bf16x8*)(Bs + cb + (ib + j) * 512 + fbg);
#pragma unroll
    for (int i = 0; i < 4; ++i)
#pragma unroll
      for (int j = 0; j < 4; ++j)
        acc[i][j] = __builtin_amdgcn_mfma_f32_16x16x32_bf16(af[i], bw[j], acc[i][j], 0, 0, 0);
  }
}

// ---------------------------------------------------------------------------
// QKV: grid.z selects {Q,K,V}. Q pre-scaled; V stored transposed vt[b,h,d,s].
// ---------------------------------------------------------------------------
__global__ __launch_bounds__(256) void gemm_qkv(
    const __bf16* __restrict__ xn,
    const __bf16* __restrict__ wqb, const __bf16* __restrict__ wkb,
    const __bf16* __restrict__ wvb,
    __bf16* __restrict__ qo, __bf16* __restrict__ ko, __bf16* __restrict__ vto)
{
  __shared__ __align__(16) __bf16 As[2 * 128 * 32];
  __shared__ __align__(16) __bf16 Bs[2 * 128 * 32];
  int bx, by; xcd_swizzle(bx, by);
  const __bf16* W = blockIdx.z == 0 ? wqb : (blockIdx.z == 1 ? wkb : wvb);
  f32x4 acc[4][4];
  gemm_core_128(xn, W, D_, D_, by * 128, bx * 128, acc, As, Bs);

  const int t = threadIdx.x, lane = t & 63, wv = t >> 6;
  const int wm = (wv >> 1) << 6, wn = (wv & 1) << 6;
  const int l15 = lane & 15, q4 = lane >> 4;
  const int row0 = by * 128 + wm;
  const int col0 = bx * 128 + wn;

  if (blockIdx.z < 2) {
    __bf16* o = blockIdx.z == 0 ? qo : ko;
    const float sc = blockIdx.z == 0 ? QSCALE : 1.0f;
#pragma unroll
    for (int i = 0; i < 4; ++i)
#pragma unroll
      for (int j = 0; j < 4; ++j)
#pragma unroll
        for (int r = 0; r < 4; ++r) {
          int row = row0 + 16 * i + q4 * 4 + r;
          int col = col0 + 16 * j + l15;
          o[(size_t)row * D_ + col] = (__bf16)(acc[i][j][r] * sc);
        }
  } else {
#pragma unroll
    for (int i = 0; i < 4; ++i)
#pragma unroll
      for (int j = 0; j < 4; ++j) {
        int tok0 = row0 + 16 * i + q4 * 4;
        int c    = col0 + 16 * j + l15;
        int b0 = tok0 >> 11, s0 = tok0 & (S_ - 1);
        int hh = c >> 6, dd = c & (DK_ - 1);
        bf16x4 pk;
#pragma unroll
        for (int r = 0; r < 4; ++r) pk[r] = (__bf16)acc[i][j][r];
        *(bf16x4*)&vto[(size_t)((b0 * H_ + hh) * DK_ + dd) * S_ + s0] = pk;
      }
  }
}

// ---------------------------------------------------------------------------
// FFN1 GEMM: h = relu(A @ W^T + bias) -> bf16.
// ---------------------------------------------------------------------------
__global__ __launch_bounds__(256) void gemm_ffn1(
    const __bf16* __restrict__ A, const __bf16* __restrict__ W,
    __bf16* __restrict__ outb, const float* __restrict__ bias)
{
  __shared__ __align__(16) __bf16 As[2 * 128 * 32];
  __shared__ __align__(16) __bf16 Bs[2 * 128 * 32];
  int bx, by; xcd_swizzle(bx, by);
  f32x4 acc[4][4];
  gemm_core_128(A, W, D_, D_, by * 128, bx * 128, acc, As, Bs);

  const int t = threadIdx.x, lane = t & 63, wv = t >> 6;
  const int wm = (wv >> 1) << 6, wn = (wv & 1) << 6;
  const int l15 = lane & 15, q4 = lane >> 4;
  const int row0 = by * 128 + wm;
  const int col0 = bx * 128 + wn;

#pragma unroll
  for (int i = 0; i < 4; ++i)
#pragma unroll
    for (int j = 0; j < 4; ++j) {
      int col = col0 + 16 * j + l15;
      float bs = bias[col];
#pragma unroll
      for (int r = 0; r < 4; ++r) {
        int row = row0 + 16 * i + q4 * 4 + r;
        float v = fmaxf(acc[i][j][r] + bs, 0.0f);
        outb[(size_t)row * DFF_ + col] = (__bf16)v;
      }
    }
}

// ---------------------------------------------------------------------------
// split-K GEMM partials (N = 1024), R7-style partial buffers (atomics
// regressed in R8: 64 MB RMW + cross-XCD line contention).
// ---------------------------------------------------------------------------
__global__ __launch_bounds__(256) void gemm_splitk_f32(
    const __bf16* __restrict__ A, const __bf16* __restrict__ W,
    int K, int kPart, float* __restrict__ pp)
{
  __shared__ __align__(16) __bf16 As[2 * 128 * 32];
  __shared__ __align__(16) __bf16 Bs[2 * 128 * 32];
  int bx, by; xcd_swizzle(bx, by);
  f32x4 acc[4][4];
  const int z = blockIdx.z;
  gemm_core_128(A + (size_t)z * kPart, W + (size_t)z * kPart, K, kPart,
                by * 128, bx * 128, acc, As, Bs);

  const int t = threadIdx.x, lane = t & 63, wv = t >> 6;
  const int wm = (wv >> 1) << 6, wn = (wv & 1) << 6;
  const int l15 = lane & 15, q4 = lane >> 4;
  const int row0 = by * 128 + wm;
  const int col0 = bx * 128 + wn;
  float* out = pp + (size_t)z * NTOK * D_;

#pragma unroll
  for (int i = 0; i < 4; ++i)
#pragma unroll
    for (int j = 0; j < 4; ++j)
#pragma unroll
      for (int r = 0; r < 4; ++r) {
        int row = row0 + 16 * i + q4 * 4 + r;
        int col = col0 + 16 * j + l15;
        out[(size_t)row * D_ + col] = acc[i][j][r];
      }
}

__global__ __launch_bounds__(256) void gemm_splitk_bf16(
    const __bf16* __restrict__ A, const __bf16* __restrict__ W,
    int K, int kPart, __bf16* __restrict__ pp)
{
  __shared__ __align__(16) __bf16 As[2 * 128 * 32];
  __shared__ __align__(16) __bf16 Bs[2 * 128 * 32];
  int bx, by; xcd_swizzle(bx, by);
  f32x4 acc[4][4];
  const int z = blockIdx.z;
  gemm_core_128(A + (size_t)z * kPart, W + (size_t)z * kPart, K, kPart,
                by * 128, bx * 128, acc, As, Bs);

  const int t = threadIdx.x, lane = t & 63, wv = t >> 6;
  const int wm = (wv >> 1) << 6, wn = (wv & 1) << 6;
  const int l15 = lane & 15, q4 = lane >> 4;
  const int row0 = by * 128 + wm;
  const int col0 = bx * 128 + wn;
  __bf16* out = pp + (size_t)z * NTOK * D_;

#pragma unroll
  for (int i = 0; i < 4; ++i)
#pragma unroll
    for (int j = 0; j < 4; ++j)
#pragma unroll
      for (int r = 0; r < 4; ++r) {
        int row = row0 + 16 * i + q4 * 4 + r;
        int col = col0 + 16 * j + l15;
        out[(size_t)row * D_ + col] = (__bf16)acc[i][j][r];
      }
}

// ---------------------------------------------------------------------------
// O-proj reduce + LN2 fused: x1 = x + p0 + p1; xn2 = LN(x1). 1 block/row.
// ---------------------------------------------------------------------------
__global__ __launch_bounds__(256) void oproj_ln_reduce(
    const float* __restrict__ x, const float* __restrict__ p0,
    const float* __restrict__ p1, const float* __restrict__ alpha,
    const float* __restrict__ bias, float* __restrict__ x1,
    __bf16* __restrict__ xn2)
{
  const int row = blockIdx.x;
  const int t = threadIdx.x;
  const size_t base = (size_t)row * D_;
  float4 v  = ((const float4*)(x  + base))[t];
  const float4 a0 = ((const float4*)(p0 + base))[t];
  const float4 a1 = ((const float4*)(p1 + base))[t];
  v.x += a0.x + a1.x; v.y += a0.y + a1.y;
  v.z += a0.z + a1.z; v.w += a0.w + a1.w;
  ((float4*)(x1 + base))[t] = v;

  float s  = v.x + v.y + v.z + v.w;
  float ss = v.x * v.x + v.y * v.y + v.z * v.z + v.w * v.w;
#pragma unroll
  for (int m = 1; m < 64; m <<= 1) {
    s  += __shfl_xor(s, m);
    ss += __shfl_xor(ss, m);
  }
  __shared__ float red[8];
  if ((t & 63) == 0) { red[t >> 6] = s; red[4 + (t >> 6)] = ss; }
  __syncthreads();
  s  = red[0] + red[1] + red[2] + red[3];
  ss = red[4] + red[5] + red[6] + red[7];
  const float mean = s * (1.0f / D_);
  float var = (ss - (float)D_ * mean * mean) * (1.0f / (D_ - 1));
  var = fmaxf(var, 0.0f);
  const float inv = 1.0f / (sqrtf(var) + 1e-6f);
  const float4 al = ((const float4*)alpha)[t];
  const float4 bi = ((const float4*)bias)[t];
  bf16x4 o;
  o.x = (__bf16)(al.x * (v.x - mean) * inv + bi.x);
  o.y = (__bf16)(al.y * (v.y - mean) * inv + bi.y);
  o.z = (__bf16)(al.z * (v.z - mean) * inv + bi.z);
  o.w = (__bf16)(al.w * (v.w - mean) * inv + bi.w);
  ((bf16x4*)(xn2 + base))[t] = o;
}

// ---------------------------------------------------------------------------
// FFN2 reduce: out = x1 + b2 + p0 + p1 (bf16 partials). 4 f32/thread.
// ---------------------------------------------------------------------------
__global__ __launch_bounds__(256) void ffn2_reduce(
    const float* __restrict__ x1, const __bf16* __restrict__ p0,
    const __bf16* __restrict__ p1, const float* __restrict__ b2,
    float* __restrict__ out)
{
  const int idx4 = blockIdx.x * 256 + threadIdx.x;
  float4 v = ((const float4*)x1)[idx4];
  const float4 bs = ((const float4*)b2)[idx4 & 255];
  const bf16x4 q0 = ((const bf16x4*)p0)[idx4];
  const bf16x4 q1 = ((const bf16x4*)p1)[idx4];
  v.x += bs.x + (float)q0[0] + (float)q1[0];
  v.y += bs.y + (float)q0[1] + (float)q1[1];
  v.z += bs.z + (float)q0[2] + (float)q1[2];
  v.w += bs.w + (float)q0[3] + (float)q1[3];
  ((float4*)out)[idx4] = v;
}

// ---------------------------------------------------------------------------
// weight f32->bf16 casts (jobs 0-5) + fused LN1 (job 6) in one launch.
// ---------------------------------------------------------------------------
struct CastJobs {
  const float* src[6];
  __bf16* dst[6];
  int n4[6];
};

__global__ __launch_bounds__(256) void cast_ln_kernel(
    CastJobs cj, const float* __restrict__ x, const float* __restrict__ alpha,
    const float* __restrict__ bias, __bf16* __restrict__ xn1)
{
  const int j = blockIdx.y;
  if (j < 6) {
    const int i = blockIdx.x * 256 + threadIdx.x;
    if (i < cj.n4[j]) {
      float4 v = ((const float4*)cj.src[j])[i];
      bf16x4 o;
      o.x = (__bf16)v.x; o.y = (__bf16)v.y; o.z = (__bf16)v.z; o.w = (__bf16)v.w;
      ((bf16x4*)cj.dst[j])[i] = o;
    }
    return;
  }
  const int row = blockIdx.x;
  const int t = threadIdx.x;
  const float4 v = ((const float4*)(x + (size_t)row * D_))[t];
  float s  = v.x + v.y + v.z + v.w;
  float ss = v.x * v.x + v.y * v.y + v.z * v.z + v.w * v.w;
#pragma unroll
  for (int m = 1; m < 64; m <<= 1) {
    s  += __shfl_xor(s, m);
    ss += __shfl_xor(ss, m);
  }
  __shared__ float red[8];
  if ((t & 63) == 0) { red[t >> 6] = s; red[4 + (t >> 6)] = ss; }
  __syncthreads();
  s  = red[0] + red[1] + red[2] + red[3];
  ss = red[4] + red[5] + red[6] + red[7];
  const float mean = s * (1.0f / D_);
  float var = (ss - (float)D_ * mean * mean) * (1.0f / (D_ - 1));
  var = fmaxf(var, 0.0f);
  const float inv = 1.0f / (sqrtf(var) + 1e-6f);
  const float4 al = ((const float4*)alpha)[t];
  const float4 bi = ((const float4*)bias)[t];
  bf16x4 o;
  o.x = (__bf16)(al.x * (v.x - mean) * inv + bi.x);
  o.y = (__bf16)(al.y * (v.y - mean) * inv + bi.y);
  o.z = (__bf16)(al.z * (v.z - mean) * inv + bi.z);
  o.w = (__bf16)(al.w * (v.w - mean) * inv + bi.w);
  ((bf16x4*)(xn1 + (size_t)row * D_))[t] = o;
}

// ---------------------------------------------------------------------------
// flash attention, BQ=128 (R7-verified): wave owns 32 q-cols, Q B-frags in
// registers, K/V LDS reads amortized over 2x MFMA. Fixed-max softmax.
// LDS = 8K(Ks)+8K(Vt)+18K(Ps) = 34 KB. Grid 512 = 2 blocks/CU.
// ---------------------------------------------------------------------------
__global__ __launch_bounds__(256) void attn_kernel(
    const __bf16* __restrict__ qg, const __bf16* __restrict__ kg,
    const __bf16* __restrict__ vtg, const int* __restrict__ mask,
    __bf16* __restrict__ av)
{
  __shared__ __align__(16) __bf16 Ks[64 * 64];
  __shared__ __align__(16) __bf16 Vt[64 * 64];
  __shared__ __align__(16) __bf16 Ps[128 * 72];

  const int t = threadIdx.x, lane = t & 63, wv = t >> 6;
  const int l15 = lane & 15, q4 = lane >> 4;
  const int bh = blockIdx.x;
  const int b = bh >> 4, h = bh & (H_ - 1);
  const int q0 = blockIdx.y * 128;

  const int srow = lane & 7, sc8 = lane >> 3;
  const __bf16* qg0 = qg + (size_t)(b * S_ + q0 + 32 * wv + srow) * D_ + h * DK_ + sc8 * 8;
  __bf16* lQ = Ps + wv * 2304;
#pragma unroll
  for (int p = 0; p < 4; ++p)
    ld16(qg0 + (size_t)(8 * p) * D_, lQ + 512 * p);

  const __bf16* kg0 = kg + (size_t)(b * S_ + 16 * wv + srow) * D_ + h * DK_ + sc8 * 8;
  const __bf16* vt0 = vtg + (size_t)(bh * DK_ + 16 * wv + srow) * S_ + sc8 * 8;

  const int fb = ((l15 >> 3) << 9) + (q4 << 6) + ((l15 & 7) << 3);
  const int mrow = b * S_;

  float lsum[2] = {0.0f, 0.0f};
  f32x4 oacc[2][4];
#pragma unroll
  for (int m = 0; m < 2; ++m)
#pragma unroll
    for (int jd = 0; jd < 4; ++jd) oacc[m][jd] = (f32x4){0.f, 0.f, 0.f, 0.f};
  bf16x8 bq[2][2];

  for (int kv0 = 0; kv0 < S_; kv0 += 64) {
    ld16(kg0 + (size_t)kv0 * D_,       Ks + wv * 1024);
    ld16(kg0 + (size_t)(kv0 + 8) * D_, Ks + wv * 1024 + 512);
    ld16(vt0 + kv0,                    Vt + wv * 1024);
    ld16(vt0 + (size_t)8 * S_ + kv0,   Vt + wv * 1024 + 512);
    const int mv = mask[mrow + kv0 + lane];
    const bool dirty = (__ballot(mv == 0) != 0ull);
    __syncthreads();

    if (kv0 == 0) {
#pragma unroll
      for (int j = 0; j < 2; ++j)
#pragma unroll
        for (int s = 0; s < 2; ++s)
          bq[j][s] = *(const bf16x8*)(lQ + j * 1024 + s * 256 + fb);
    }

    f32x4 sacc[4][2];
#pragma unroll
    for (int i = 0; i < 4; ++i)
#pragma unroll
      for (int j = 0; j < 2; ++j) sacc[i][j] = (f32x4){0.f, 0.f, 0.f, 0.f};
#pragma unroll
    for (int i = 0; i < 4; ++i)
#pragma unroll
      for (int s = 0; s < 2; ++s) {
        bf16x8 ak = *(const bf16x8*)(Ks + i * 1024 + fb + s * 256);
#pragma unroll
        for (int j = 0; j < 2; ++j)
          sacc[i][j] = __builtin_amdgcn_mfma_f32_16x16x32_bf16(ak, bq[j][s], sacc[i][j], 0, 0, 0);
      }

    if (dirty) {
#pragma unroll
      for (int i = 0; i < 4; ++i)
#pragma unroll
        for (int r = 0; r < 4; ++r)
          if (mask[mrow + kv0 + 16 * i + 4 * q4 + r] == 0) {
            sacc[i][0][r] = -1e30f;
            sacc[i][1][r] = -1e30f;
          }
    }

#pragma unroll
    for (int j = 0; j < 2; ++j) {
      float rs = 0.0f;
#pragma unroll
      for (int i = 0; i < 4; ++i) {
        bf16x4 pb;
#pragma unroll
        for (int r = 0; r < 4; ++r) {
          float pp = EXP2(sacc[i][j][r]);
          rs += pp;
          pb[r] = (__bf16)pp;
        }
        *(bf16x4*)(Ps + (wv * 32 + j * 16 + l15) * 72 + 16 * i + q4 * 4) = pb;
      }
      lsum[j] += rs;
    }

    bf16x8 ap[2][2];
#pragma unroll
    for (int m = 0; m < 2; ++m)
#pragma unroll
      for (int s = 0; s < 2; ++s)
        ap[m][s] = *(const bf16x8*)(Ps + (wv * 32 + 16 * m + l15) * 72 + s * 32 + q4 * 8);
#pragma unroll
    for (int jd = 0; jd < 4; ++jd)
#pragma unroll
      for (int s = 0; s < 2; ++s) {
        bf16x8 bv = *(const bf16x8*)(Vt + jd * 1024 + fb + s * 256);
#pragma unroll
        for (int m = 0; m < 2; ++m)
          oacc[m][jd] = __builtin_amdgcn_mfma_f32_16x16x32_bf16(ap[m][s], bv, oacc[m][jd], 0, 0, 0);
      }
    __syncthreads();
  }

#pragma unroll
  for (int j = 0; j < 2; ++j) {
    lsum[j] += __shfl_xor(lsum[j], 16);
    lsum[j] += __shfl_xor(lsum[j], 32);
  }
  float lt[2][4];
#pragma unroll
  for (int m = 0; m < 2; ++m)
#pragma unroll
    for (int r = 0; r < 4; ++r) lt[m][r] = 1.0f / __shfl(lsum[m], q4 * 4 + r);
#pragma unroll
  for (int m = 0; m < 2; ++m)
#pragma unroll
    for (int jd = 0; jd < 4; ++jd)
#pragma unroll
      for (int r = 0; r < 4; ++r) {
        int tok = b * S_ + q0 + wv * 32 + 16 * m + q4 * 4 + r;
        int c   = h * DK_ + jd * 16 + l15;
        av[(size_t)tok * D_ + c] = (__bf16)(oacc[m][jd][r] * lt[m][r]);
      }
}

// ---------------------------------------------------------------------------
extern "C" void kernel_launch(void* const* d_in, const int* in_sizes, int n_in,
                              void* d_out, int out_size, void* d_ws, size_t ws_size,
                              hipStream_t stream) {
  const float* x      = (const float*)d_in[0];
  const int*   mask   = (const int*)d_in[1];
  const float* wq     = (const float*)d_in[2];
  const float* wk     = (const float*)d_in[3];
  const float* wv     = (const float*)d_in[4];
  const float* wo     = (const float*)d_in[5];
  const float* w1     = (const float*)d_in[6];
  const float* b1     = (const float*)d_in[7];
  const float* w2     = (const float*)d_in[8];
  const float* b2     = (const float*)d_in[9];
  const float* alpha1 = (const float*)d_in[10];
  const float* bias1  = (const float*)d_in[11];
  const float* alpha2 = (const float*)d_in[12];
  const float* bias2  = (const float*)d_in[13];

  // ws layout (MB offsets), peak 80 MB — R7 scheme.
  char* ws = (char*)d_ws;
  __bf16* wqb = (__bf16*)(ws + ((size_t)0 << 20));
  __bf16* wkb = (__bf16*)(ws + ((size_t)2 << 20));
  __bf16* wvb = (__bf16*)(ws + ((size_t)4 << 20));
  __bf16* wob = (__bf16*)(ws + ((size_t)6 << 20));
  __bf16* w1b = (__bf16*)(ws + ((size_t)8 << 20));
  __bf16* w2b = (__bf16*)(ws + ((size_t)16 << 20));
  __bf16* xn1 = (__bf16*)(ws + ((size_t)24 << 20));
  __bf16* qb  = (__bf16*)(ws + ((size_t)32 << 20));
  __bf16* kb  = (__bf16*)(ws + ((size_t)40 << 20));
  __bf16* vtb = (__bf16*)(ws + ((size_t)48 << 20));
  __bf16* avb = (__bf16*)(ws + ((size_t)56 << 20));
  float*  x1  = (float*) (ws + ((size_t)64 << 20));
  __bf16* xn2 = (__bf16*)(ws + ((size_t)56 << 20));
  __bf16* hb  = (__bf16*)(ws + ((size_t)24 << 20));
  float*  op0 = (float*) (ws + ((size_t)24 << 20));
  float*  op1 = (float*) (ws + ((size_t)40 << 20));
  __bf16* fp0 = (__bf16*)(ws + ((size_t)0 << 20));
  __bf16* fp1 = (__bf16*)(ws + ((size_t)8 << 20));

  CastJobs cj;
  cj.src[0] = wq; cj.dst[0] = wqb; cj.n4[0] = D_ * D_ / 4;
  cj.src[1] = wk; cj.dst[1] = wkb; cj.n4[1] = D_ * D_ / 4;
  cj.src[2] = wv; cj.dst[2] = wvb; cj.n4[2] = D_ * D_ / 4;
  cj.src[3] = wo; cj.dst[3] = wob; cj.n4[3] = D_ * D_ / 4;
  cj.src[4] = w1; cj.dst[4] = w1b; cj.n4[4] = DFF_ * D_ / 4;
  cj.src[5] = w2; cj.dst[5] = w2b; cj.n4[5] = DFF_ * D_ / 4;

  cast_ln_kernel<<<dim3(DFF_ * D_ / 4 / 256, 7), 256, 0, stream>>>(
      cj, x, alpha1, bias1, xn1);

  gemm_qkv<<<dim3(D_ / 128, NTOK / 128, 3), 256, 0, stream>>>(
      xn1, wqb, wkb, wvb, qb, kb, vtb);

  attn_kernel<<<dim3(B_ * H_, S_ / 128), 256, 0, stream>>>(qb, kb, vtb, mask, avb);

  gemm_splitk_f32<<<dim3(D_ / 128, NTOK / 128, 2), 256, 0, stream>>>(
      avb, wob, D_, D_ / 2, op0);

  oproj_ln_reduce<<<dim3(NTOK), 256, 0, stream>>>(
      x, op0, op1, alpha2, bias2, x1, xn2);

  gemm_ffn1<<<dim3(DFF_ / 128, NTOK / 128), 256, 0, stream>>>(
      xn2, w1b, hb, b1);

  gemm_splitk_bf16<<<dim3(D_ / 128, NTOK / 128, 2), 256, 0, stream>>>(
      hb, w2b, DFF_, DFF_ / 2, fp0);

  ffn2_reduce<<<dim3(NTOK * D_ / 4 / 256), 256, 0, stream>>>(
      x1, fp0, fp1, b2, (float*)d_out);
}